// Round 6
// baseline (195.645 us; speedup 1.0000x reference)
//
#include <hip/hip_runtime.h>
#include <math.h>

// GraphAttentionBlock: B=1, N=4096, E=256, H=8, D=32, fp32 in/out.
// R19: attn occupancy push. R18 analysis: per-wave tile body is a serial
// chain (S-MFMA -> exp2 -> pack -> LDS -> PV-MFMA -> barrier) and the grid
// (1024 blocks of 4 waves) only offers 4 blocks/CU (measured 2.5 resident,
// 31% occ) -- latency-bound, not VALU-saturated (VALUBusy 40%). Blocks
// shrunk to 2 waves / 32 q-rows, grid (128,8,2) = 2048 blocks = 8/CU =
// 16 waves/CU. Per-wave work unchanged; staging DMA now 4 instr/wave/tile
// (K: 2, V: 2); barrier groups 4->2 waves. Tile body byte-identical to
// verified R18 (DMA-linear K [64][32], pre-swizzled-source V [32][64] with
// same XOR on read, P_lds, lacc MFMA denominator, setprio). 4 launches.

#define NTOK 4096
#define EDIM 256
#define HEADS 8
#define HD 32
#define NSPLIT 2
#define QSCALE 0.17677669529663687f            // 1/sqrt(32)
#define LOG2E 1.4426950408889634f
#define CINIT (-11.541560327111707f)           // -8 * log2(e)

typedef __attribute__((ext_vector_type(8))) short bf16x8;
typedef __attribute__((ext_vector_type(4))) float f32x4;
typedef __attribute__((ext_vector_type(4))) unsigned long long u64x4;

typedef __attribute__((address_space(3))) unsigned char lds_u8;
typedef const __attribute__((address_space(1))) unsigned char gl_u8;

static __device__ inline short f2bf(float f) {          // RNE
    unsigned u = __float_as_uint(f);
    u = (u + 0x7FFFu + ((u >> 16) & 1u)) >> 16;
    return (short)u;
}
// truncating bf16x2 pack: one v_perm_b32 (hi16 of a -> lo, hi16 of b -> hi)
static __device__ inline unsigned packtrunc(float a, float b) {
    return __builtin_amdgcn_perm(__float_as_uint(b), __float_as_uint(a),
                                 0x07060302u);
}
// p = (mask bit for this lane) ? v : 0   -- one VALU op, sgpr-pair mask
static __device__ inline float sel_mask(float v, unsigned long long m) {
    float r;
    asm("v_cndmask_b32 %0, 0, %1, %2" : "=v"(r) : "v"(v), "s"(m));
    return r;
}

// ---- prep: adjacency -> S^T bitmask + bf16 casts --------------------------
// maskT[qb*1024+kt*16+b*4+j] bit l = adj[qb*16+(l&15)][kt*64+b*16+((l>>4)&3)*4+j]
// mask work batched: 2048 blocks x 4 wave-units x 8 iterations (w stride 8192)
__global__ __launch_bounds__(256) void prep(
    const int* __restrict__ adj, unsigned long long* __restrict__ maskT,
    const float* __restrict__ x,  const float* __restrict__ Wq,
    const float* __restrict__ Wk, const float* __restrict__ Wv,
    const float* __restrict__ Wo,
    short* __restrict__ xb,  short* __restrict__ wqb,
    short* __restrict__ wkb, short* __restrict__ wvb,
    short* __restrict__ wob)
{
    const int bid = blockIdx.x;
    if (bid < 2048) {
        const int wb = bid * 4 + (threadIdx.x >> 6);
        const int l = threadIdx.x & 63;
        const int lrow = l & 15;
        const int lc4 = ((l >> 4) & 3) * 4;
#pragma unroll
        for (int i = 0; i < 8; ++i) {
            const int w = wb + i * 8192;             // (qb,kt,b)
            const int qb = w >> 8;
            const int kt = (w >> 2) & 63;
            const int b = w & 3;
            const int row = qb * 16 + lrow;
            const int col = kt * 64 + b * 16 + lc4;
            const int4 av = *(const int4*)&adj[row * NTOK + col];
            const unsigned long long m0 = __ballot(av.x != 0);
            const unsigned long long m1 = __ballot(av.y != 0);
            const unsigned long long m2 = __ballot(av.z != 0);
            const unsigned long long m3 = __ballot(av.w != 0);
            if (l == 0) {
                unsigned long long* dst = &maskT[(size_t)w * 4];
                dst[0] = m0; dst[1] = m1; dst[2] = m2; dst[3] = m3;
            }
        }
    } else {
        const int gid = (bid - 2048) * 256 + threadIdx.x;
        const int e = gid * 4;
        const float* src; short* dst; int off;
        if (e < NTOK * EDIM) { src = x; dst = xb; off = e; }
        else {
            const int r = e - NTOK * EDIM;
            const int wsel = r >> 16;
            off = r & 65535;
            src = (wsel == 0) ? Wq : (wsel == 1) ? Wk : (wsel == 2) ? Wv : Wo;
            dst = (wsel == 0) ? wqb : (wsel == 1) ? wkb : (wsel == 2) ? wvb : wob;
        }
        float4 v = *(const float4*)&src[off];
        uint2 t;
        t.x = (unsigned short)f2bf(v.x) | ((unsigned)(unsigned short)f2bf(v.y) << 16);
        t.y = (unsigned short)f2bf(v.z) | ((unsigned)(unsigned short)f2bf(v.w) << 16);
        *(uint2*)&dst[off] = t;
    }
}

// ---- QKV projection via MFMA, 16x64 per wave; q/k head-major, v transposed
__global__ __launch_bounds__(256) void qkv_mfma(
    const short* __restrict__ xb,
    const short* __restrict__ Wqb, const short* __restrict__ Wkb,
    const short* __restrict__ Wvb,
    const float* __restrict__ bq, const float* __restrict__ bk,
    const float* __restrict__ bv,
    short* __restrict__ qo, short* __restrict__ ko, short* __restrict__ vto)
{
    const int tid = threadIdx.x;
    const int wv = tid >> 6, lane = tid & 63;
    const int grp = lane >> 4, lcol = lane & 15;
    const int wsel = blockIdx.y >> 2;                  // 0=Q 1=K 2=V
    const int n0 = (blockIdx.y & 3) << 6;
    const int m0 = blockIdx.x * 64 + wv * 16;
    const short* __restrict__ W = (wsel == 0) ? Wqb : (wsel == 1) ? Wkb : Wvb;
    const float* __restrict__ bias = (wsel == 0) ? bq : (wsel == 1) ? bk : bv;

    bf16x8 af[8];
#pragma unroll
    for (int k = 0; k < 8; ++k)
        af[k] = *(const bf16x8*)&xb[(m0 + lcol) * 256 + k * 32 + grp * 8];

    f32x4 acc[4] = {};
#pragma unroll
    for (int k = 0; k < 8; ++k) {
#pragma unroll
        for (int t = 0; t < 4; ++t) {
            const bf16x8 bt =
                *(const bf16x8*)&W[(n0 + t * 16 + lcol) * 256 + k * 32 + grp * 8];
            acc[t] = __builtin_amdgcn_mfma_f32_16x16x32_bf16(af[k], bt, acc[t], 0, 0, 0);
        }
    }
#pragma unroll
    for (int t = 0; t < 4; ++t) {
        const int feat = n0 + t * 16 + lcol;
        const float bval = bias[feat];
        const int h = feat >> 5, d = feat & 31;
        if (wsel == 2) {
            uint2 o;
            o.x = (unsigned short)f2bf(acc[t][0] + bval) |
                  ((unsigned)(unsigned short)f2bf(acc[t][1] + bval) << 16);
            o.y = (unsigned short)f2bf(acc[t][2] + bval) |
                  ((unsigned)(unsigned short)f2bf(acc[t][3] + bval) << 16);
            *(uint2*)&vto[h * (HD * NTOK) + d * NTOK + m0 + grp * 4] = o;
        } else {
            short* __restrict__ out = (wsel == 0) ? qo : ko;
            // fold 1/sqrt(D) * log2(e) into Q so attn uses raw exp2
            const float sc = (wsel == 0) ? (QSCALE * LOG2E) : 1.0f;
#pragma unroll
            for (int j = 0; j < 4; ++j)
                out[h * (NTOK * HD) + (m0 + grp * 4 + j) * HD + d] =
                    f2bf((acc[t][j] + bval) * sc);
        }
    }
}

// ---- MFMA flash attention: 2-wave blocks, global_load_lds staging --------
__global__ __launch_bounds__(128) void attn_mfma(
    const short* __restrict__ qg, const short* __restrict__ kg,
    const short* __restrict__ vtg, const unsigned long long* __restrict__ maskT,
    float* __restrict__ o_part, float* __restrict__ l_part)
{
    const int h = blockIdx.y;
    const int split = blockIdx.z;
    const int q0 = blockIdx.x << 5;                 // 32 q-rows per block
    const short* __restrict__ Q  = qg  + h * (NTOK * HD);
    const short* __restrict__ K  = kg  + h * (NTOK * HD);
    const short* __restrict__ Vt = vtg + h * (HD * NTOK);

    __shared__ short Ks[2][64][32];      // 64B rows, DMA-linear
    __shared__ short Vs[2][32][64];      // 128B rows, octet-XOR swizzled
    __shared__ short P_lds[2][16][76];   // 152B rows (wave-private)

    const int tid = threadIdx.x;
    const int wv = tid >> 6;
    const int lane = tid & 63;
    const int grp = lane >> 4;
    const int lcol = lane & 15;
    const int q0w = q0 + wv * 16;
    const int wvu = __builtin_amdgcn_readfirstlane(wv);

    // DMA source lane-coords for the 2-instr-per-buffer split (i = 0,1):
    //   K dest byte = wv*2048 + i*1024 + lane*16 -> row wv*32+i*16+(lane>>2)
    //   V dest byte = wv*2048 + i*1024 + lane*16 -> row wv*16+i*8+(lane>>3)
    const int k_row0 = wvu * 32 + (lane >> 2);          // i=0 row
    const int k_oct = lane & 3;
    const int v_row0 = wvu * 16 + (lane >> 3);          // i=0 row
    const int v_p = lane & 7;
    const short* __restrict__ kb0 = &K[k_row0 * HD + k_oct * 8];
    const short* __restrict__ kb1 = &K[(k_row0 + 16) * HD + k_oct * 8];
    const short* __restrict__ vb0 =
        &Vt[v_row0 * NTOK + (v_p ^ (v_row0 & 7)) * 8];
    const short* __restrict__ vb1 =
        &Vt[(v_row0 + 8) * NTOK + (v_p ^ ((v_row0 + 8) & 7)) * 8];

    // Q as B-operand: B[n=lcol(qrow)][k=grp*8+j(d)]
    const bf16x8 qfrag = *(const bf16x8*)&Q[(q0w + lcol) * HD + grp * 8];

    const int qb = __builtin_amdgcn_readfirstlane(blockIdx.x * 2 + wv);
    const unsigned long long* __restrict__ mbase = maskT + (size_t)qb * 1024;

    f32x4 ot[2] = {};     // O^T C-layout: row=grp*4+j (d), col=lcol (qrow)
    f32x4 lacc = {};      // column sums of P via mfma(ones, pf, .)
    const f32x4 cinit = {CINIT, CINIT, CINIT, CINIT};
    bf16x8 ones;
#pragma unroll
    for (int i = 0; i < 8; ++i) ones[i] = (short)0x3F80;   // bf16 1.0

    const int tps = 64 / (int)gridDim.z;   // 64-key tiles per split
    const int kt_begin = split * tps;
    const int kt_end = kt_begin + tps;

// async DMA one 64-key tile (4KB K + 4KB V) into buffer BUF; each wave
// fills its 2KB half of each via 2 instrs (lane l -> base + l*16B)
#define STAGE(BUF, KT)                                                       \
    {                                                                        \
        const int k0s = (KT) << 6;                                           \
        unsigned char* kd =                                                  \
            (unsigned char*)&Ks[BUF][0][0] + (wvu << 11);                    \
        unsigned char* vd =                                                  \
            (unsigned char*)&Vs[BUF][0][0] + (wvu << 11);                    \
        __builtin_amdgcn_global_load_lds((gl_u8*)(kb0 + k0s * HD),           \
                                         (lds_u8*)kd, 16, 0, 0);             \
        __builtin_amdgcn_global_load_lds((gl_u8*)(kb1 + k0s * HD),           \
                                         (lds_u8*)(kd + 1024), 16, 0, 0);    \
        __builtin_amdgcn_global_load_lds((gl_u8*)(vb0 + k0s),                \
                                         (lds_u8*)vd, 16, 0, 0);             \
        __builtin_amdgcn_global_load_lds((gl_u8*)(vb1 + k0s),                \
                                         (lds_u8*)(vd + 1024), 16, 0, 0);    \
    }

    STAGE(0, kt_begin)
    __syncthreads();                       // drains vmcnt -> tile 0 ready

    int cur = 0;
    for (int kt = kt_begin; kt < kt_end; ++kt) {
        // issue next tile's DMA into the other buffer (async, vmcnt-tracked)
        if (kt + 1 < kt_end) STAGE(cur ^ 1, kt + 1)

        // mask words for this tile (contiguous scalar region)
        const u64x4* mp = (const u64x4*)(mbase + kt * 16);
        const u64x4 wa = mp[0], wb = mp[1], wc = mp[2], wd = mp[3];

        // fragments from shared LDS tiles
        bf16x8 kf[4], vf[4];
#pragma unroll
        for (int b = 0; b < 4; ++b)
            kf[b] = *(const bf16x8*)&Ks[cur][b * 16 + lcol][grp * 8];
#pragma unroll
        for (int c = 0; c < 2; ++c) {
            vf[c * 2 + 0] =
                *(const bf16x8*)&Vs[cur][c * 16 + lcol][(grp ^ (lcol & 7)) * 8];
            vf[c * 2 + 1] =
                *(const bf16x8*)&Vs[cur][c * 16 + lcol][((4 + grp) ^ (lcol & 7)) * 8];
        }

        // S^T = K Q^T - 8*log2e: row=key_in_blk, col=qrow (log2-domain)
        f32x4 s[4];
        __builtin_amdgcn_s_setprio(1);
#pragma unroll
        for (int b = 0; b < 4; ++b)
            s[b] = __builtin_amdgcn_mfma_f32_16x16x32_bf16(
                kf[b], qfrag, cinit, 0, 0, 0);
        __builtin_amdgcn_s_setprio(0);

        // p = exp2(s) masked; truncating v_perm pack; ds_write_b64
#pragma unroll
        for (int b = 0; b < 4; ++b) {
            const u64x4 wj = (b == 0) ? wa : (b == 1) ? wb : (b == 2) ? wc : wd;
            const float p0 = sel_mask(__builtin_amdgcn_exp2f(s[b][0]), wj[0]);
            const float p1 = sel_mask(__builtin_amdgcn_exp2f(s[b][1]), wj[1]);
            const float p2 = sel_mask(__builtin_amdgcn_exp2f(s[b][2]), wj[2]);
            const float p3 = sel_mask(__builtin_amdgcn_exp2f(s[b][3]), wj[3]);
            uint2 t;
            t.x = packtrunc(p0, p1);
            t.y = packtrunc(p2, p3);
            *(uint2*)&P_lds[wv][lcol][b * 16 + grp * 4] = t;
        }

        // P as B-operand: row-contiguous b64 pairs
        const uint2 pl0 = *(const uint2*)&P_lds[wv][lcol][grp * 8];
        const uint2 pl1 = *(const uint2*)&P_lds[wv][lcol][grp * 8 + 4];
        const uint2 pl2 = *(const uint2*)&P_lds[wv][lcol][32 + grp * 8];
        const uint2 pl3 = *(const uint2*)&P_lds[wv][lcol][32 + grp * 8 + 4];
        struct { uint2 a, b; } u0 = {pl0, pl1}, u1 = {pl2, pl3};
        const bf16x8 pf0 = __builtin_bit_cast(bf16x8, u0);
        const bf16x8 pf1 = __builtin_bit_cast(bf16x8, u1);

        __builtin_amdgcn_s_setprio(1);
#pragma unroll
        for (int c = 0; c < 2; ++c) {
            ot[c] = __builtin_amdgcn_mfma_f32_16x16x32_bf16(vf[c * 2 + 0], pf0, ot[c], 0, 0, 0);
            ot[c] = __builtin_amdgcn_mfma_f32_16x16x32_bf16(vf[c * 2 + 1], pf1, ot[c], 0, 0, 0);
        }
        lacc = __builtin_amdgcn_mfma_f32_16x16x32_bf16(ones, pf0, lacc, 0, 0, 0);
        lacc = __builtin_amdgcn_mfma_f32_16x16x32_bf16(ones, pf1, lacc, 0, 0, 0);
        __builtin_amdgcn_s_setprio(0);

        // one barrier: implicit vmcnt(0) drain also completes next-tile DMA
        __syncthreads();
        cur ^= 1;
    }
#undef STAGE

    float* __restrict__ ob = o_part + split * (NTOK * EDIM);
#pragma unroll
    for (int c = 0; c < 2; ++c) {
        float4 st;
        st.x = ot[c][0]; st.y = ot[c][1]; st.z = ot[c][2]; st.w = ot[c][3];
        *(float4*)&ob[(q0w + lcol) * EDIM + h * HD + c * 16 + grp * 4] = st;
    }
    // every lane holds l[qrow] in lacc[0] (A=ones -> all C-rows equal)
    if (grp == 0)
        l_part[split * (NTOK * HEADS) + (q0w + lcol) * HEADS + h] = lacc[0];
}

// ---- output projection, combine fused: Y = ((Σo)/(Σl)) @ Wo^T + bo -------
// R13 tiling: grid (64,4), 64 rows/block, 4 n-tiles per wave (af reused 4x).
// NS compile-time so split-loads fully unroll and overlap.
template <int NS>
__global__ __launch_bounds__(256) void out_mfma(
    const float* __restrict__ o_part, const float* __restrict__ l_part,
    const short* __restrict__ Wob, const float* __restrict__ bo,
    float* __restrict__ Y)
{
    const int tid = threadIdx.x;
    const int wv = tid >> 6, lane = tid & 63;
    const int grp = lane >> 4, lcol = lane & 15;
    const int n0 = blockIdx.y << 6;
    const int m0 = blockIdx.x * 64 + wv * 16;
    const int r = m0 + lcol;

    bf16x8 af[8];
#pragma unroll
    for (int k = 0; k < 8; ++k) {
        float4 s0 = {0.f, 0.f, 0.f, 0.f}, s1 = {0.f, 0.f, 0.f, 0.f};
        float lv = 0.f;
#pragma unroll
        for (int s = 0; s < NS; ++s) {
            const float* op = &o_part[s * (NTOK * EDIM) + r * EDIM + k * 32 + grp * 8];
            const float4 t0 = *(const float4*)op;
            const float4 t1 = *(const float4*)(op + 4);
            s0.x += t0.x; s0.y += t0.y; s0.z += t0.z; s0.w += t0.w;
            s1.x += t1.x; s1.y += t1.y; s1.z += t1.z; s1.w += t1.w;
            lv += l_part[s * (NTOK * HEADS) + r * HEADS + k];
        }
        const float inv = 1.0f / lv;
        bf16x8 t;
        t[0] = f2bf(s0.x * inv); t[1] = f2bf(s0.y * inv);
        t[2] = f2bf(s0.z * inv); t[3] = f2bf(s0.w * inv);
        t[4] = f2bf(s1.x * inv); t[5] = f2bf(s1.y * inv);
        t[6] = f2bf(s1.z * inv); t[7] = f2bf(s1.w * inv);
        af[k] = t;
    }

    f32x4 acc[4] = {};
#pragma unroll
    for (int k = 0; k < 8; ++k) {
#pragma unroll
        for (int t = 0; t < 4; ++t) {
            const bf16x8 bt =
                *(const bf16x8*)&Wob[(n0 + t * 16 + lcol) * 256 + k * 32 + grp * 8];
            acc[t] = __builtin_amdgcn_mfma_f32_16x16x32_bf16(af[k], bt, acc[t], 0, 0, 0);
        }
    }
#pragma unroll
    for (int t = 0; t < 4; ++t) {
        const float bval = bo[n0 + t * 16 + lcol];
#pragma unroll
        for (int j = 0; j < 4; ++j)
            Y[(m0 + grp * 4 + j) * EDIM + n0 + t * 16 + lcol] = acc[t][j] + bval;
    }
}

extern "C" void kernel_launch(void* const* d_in, const int* in_sizes, int n_in,
                              void* d_out, int out_size, void* d_ws, size_t ws_size,
                              hipStream_t stream) {
    (void)in_sizes; (void)n_in; (void)out_size; (void)ws_size;
    const float* x  = (const float*)d_in[0];
    const int*  adj = (const int*)d_in[1];
    const float* Wq = (const float*)d_in[2];
    const float* bq = (const float*)d_in[3];
    const float* Wk = (const float*)d_in[4];
    const float* bk = (const float*)d_in[5];
    const float* Wv = (const float*)d_in[6];
    const float* bv = (const float*)d_in[7];
    const float* Wo = (const float*)d_in[8];
    const float* bo = (const float*)d_in[9];

    char* ws = (char*)d_ws;
    short* x_bf  = (short*)(ws);                        // 2 MB  [N][256]
    short* q_ws  = (short*)(ws + (2u << 20));           // 2 MB  [H][N][32]
    short* k_ws  = (short*)(ws + (4u << 20));           // 2 MB
    short* vt_ws = (short*)(ws + (6u << 20));           // 2 MB  [H][32][N]
    unsigned long long* maskT =
        (unsigned long long*)(ws + (8u << 20));         // 2 MB
    short* Wq_bf = (short*)(ws + (10u << 20));          // 128 KB each
    short* Wk_bf = Wq_bf + (EDIM * EDIM);
    short* Wv_bf = Wk_bf + (EDIM * EDIM);
    short* Wo_bf = Wv_bf + (EDIM * EDIM);
    float* l_part = (float*)(ws + (11u << 20));         // 256 KB [2][N][8]
    float* o_part = (float*)(ws + (12u << 20));         // 8 MB   [2][N][256]

    prep<<<dim3(2048 + 1280), 256, 0, stream>>>(
        adj, maskT, x, Wq, Wk, Wv, Wo, x_bf, Wq_bf, Wk_bf, Wv_bf, Wo_bf);
    qkv_mfma<<<dim3(64, 12), 256, 0, stream>>>(x_bf, Wq_bf, Wk_bf, Wv_bf,
                                               bq, bk, bv, q_ws, k_ws, vt_ws);
    attn_mfma<<<dim3(128, HEADS, NSPLIT), 128, 0, stream>>>(
        q_ws, k_ws, vt_ws, maskT, o_part, l_part);
    out_mfma<NSPLIT><<<dim3(64, 4), 256, 0, stream>>>(o_part, l_part, Wo_bf, bo,
                                                      (float*)d_out);
}

// Round 7
// 175.380 us; speedup vs baseline: 1.1155x; 1.1155x over previous
//
#include <hip/hip_runtime.h>
#include <math.h>

// GraphAttentionBlock: B=1, N=4096, E=256, H=8, D=32, fp32 in/out.
// R20: R19's 2-wave blocks reverted (duplicated staging per block: attn
// 61.5us, occ 23%). Back to R18 structure (4 waves, 64 q, 256 thr), with
// the per-tile __syncthreads (vmcnt(0) DRAIN) replaced by T4 counted
// vmcnt + raw s_barrier + 3-buffer rotation staged 2 tiles ahead:
//   iter t: s_waitcnt vmcnt(2)  (in-order retirement -> tile t landed,
//           tile t+1's 2 DMA ops may stay in flight ACROSS the barrier)
//           s_barrier; sched_barrier(0); masks; STAGE(t+2); compute buf t%3.
//   last iter: vmcnt(0). Race-safe: buf b (tile t) overwritten only by
//   STAGE(t+3) issued after the top-of-iter-t+1 barrier (all waves done
//   reading t); masks loaded before STAGE so any pre-use wait is vmcnt(2).
// LDS 3x(4K+4K)+9.7K = 33.7KB -> still 4 blocks/CU. Tile body, staging
// addresses, numerics byte-identical to verified R18. 4 launches.

#define NTOK 4096
#define EDIM 256
#define HEADS 8
#define HD 32
#define NSPLIT 2
#define QSCALE 0.17677669529663687f            // 1/sqrt(32)
#define LOG2E 1.4426950408889634f
#define CINIT (-11.541560327111707f)           // -8 * log2(e)

typedef __attribute__((ext_vector_type(8))) short bf16x8;
typedef __attribute__((ext_vector_type(4))) float f32x4;
typedef __attribute__((ext_vector_type(4))) unsigned long long u64x4;

typedef __attribute__((address_space(3))) unsigned char lds_u8;
typedef const __attribute__((address_space(1))) unsigned char gl_u8;

static __device__ inline short f2bf(float f) {          // RNE
    unsigned u = __float_as_uint(f);
    u = (u + 0x7FFFu + ((u >> 16) & 1u)) >> 16;
    return (short)u;
}
// truncating bf16x2 pack: one v_perm_b32 (hi16 of a -> lo, hi16 of b -> hi)
static __device__ inline unsigned packtrunc(float a, float b) {
    return __builtin_amdgcn_perm(__float_as_uint(b), __float_as_uint(a),
                                 0x07060302u);
}
// p = (mask bit for this lane) ? v : 0   -- one VALU op, sgpr-pair mask
static __device__ inline float sel_mask(float v, unsigned long long m) {
    float r;
    asm("v_cndmask_b32 %0, 0, %1, %2" : "=v"(r) : "v"(v), "s"(m));
    return r;
}

// ---- prep: adjacency -> S^T bitmask + bf16 casts --------------------------
// maskT[qb*1024+kt*16+b*4+j] bit l = adj[qb*16+(l&15)][kt*64+b*16+((l>>4)&3)*4+j]
// mask work batched: 2048 blocks x 4 wave-units x 8 iterations (w stride 8192)
__global__ __launch_bounds__(256) void prep(
    const int* __restrict__ adj, unsigned long long* __restrict__ maskT,
    const float* __restrict__ x,  const float* __restrict__ Wq,
    const float* __restrict__ Wk, const float* __restrict__ Wv,
    const float* __restrict__ Wo,
    short* __restrict__ xb,  short* __restrict__ wqb,
    short* __restrict__ wkb, short* __restrict__ wvb,
    short* __restrict__ wob)
{
    const int bid = blockIdx.x;
    if (bid < 2048) {
        const int wb = bid * 4 + (threadIdx.x >> 6);
        const int l = threadIdx.x & 63;
        const int lrow = l & 15;
        const int lc4 = ((l >> 4) & 3) * 4;
#pragma unroll
        for (int i = 0; i < 8; ++i) {
            const int w = wb + i * 8192;             // (qb,kt,b)
            const int qb = w >> 8;
            const int kt = (w >> 2) & 63;
            const int b = w & 3;
            const int row = qb * 16 + lrow;
            const int col = kt * 64 + b * 16 + lc4;
            const int4 av = *(const int4*)&adj[row * NTOK + col];
            const unsigned long long m0 = __ballot(av.x != 0);
            const unsigned long long m1 = __ballot(av.y != 0);
            const unsigned long long m2 = __ballot(av.z != 0);
            const unsigned long long m3 = __ballot(av.w != 0);
            if (l == 0) {
                unsigned long long* dst = &maskT[(size_t)w * 4];
                dst[0] = m0; dst[1] = m1; dst[2] = m2; dst[3] = m3;
            }
        }
    } else {
        const int gid = (bid - 2048) * 256 + threadIdx.x;
        const int e = gid * 4;
        const float* src; short* dst; int off;
        if (e < NTOK * EDIM) { src = x; dst = xb; off = e; }
        else {
            const int r = e - NTOK * EDIM;
            const int wsel = r >> 16;
            off = r & 65535;
            src = (wsel == 0) ? Wq : (wsel == 1) ? Wk : (wsel == 2) ? Wv : Wo;
            dst = (wsel == 0) ? wqb : (wsel == 1) ? wkb : (wsel == 2) ? wvb : wob;
        }
        float4 v = *(const float4*)&src[off];
        uint2 t;
        t.x = (unsigned short)f2bf(v.x) | ((unsigned)(unsigned short)f2bf(v.y) << 16);
        t.y = (unsigned short)f2bf(v.z) | ((unsigned)(unsigned short)f2bf(v.w) << 16);
        *(uint2*)&dst[off] = t;
    }
}

// ---- QKV projection via MFMA, 16x64 per wave; q/k head-major, v transposed
__global__ __launch_bounds__(256) void qkv_mfma(
    const short* __restrict__ xb,
    const short* __restrict__ Wqb, const short* __restrict__ Wkb,
    const short* __restrict__ Wvb,
    const float* __restrict__ bq, const float* __restrict__ bk,
    const float* __restrict__ bv,
    short* __restrict__ qo, short* __restrict__ ko, short* __restrict__ vto)
{
    const int tid = threadIdx.x;
    const int wv = tid >> 6, lane = tid & 63;
    const int grp = lane >> 4, lcol = lane & 15;
    const int wsel = blockIdx.y >> 2;                  // 0=Q 1=K 2=V
    const int n0 = (blockIdx.y & 3) << 6;
    const int m0 = blockIdx.x * 64 + wv * 16;
    const short* __restrict__ W = (wsel == 0) ? Wqb : (wsel == 1) ? Wkb : Wvb;
    const float* __restrict__ bias = (wsel == 0) ? bq : (wsel == 1) ? bk : bv;

    bf16x8 af[8];
#pragma unroll
    for (int k = 0; k < 8; ++k)
        af[k] = *(const bf16x8*)&xb[(m0 + lcol) * 256 + k * 32 + grp * 8];

    f32x4 acc[4] = {};
#pragma unroll
    for (int k = 0; k < 8; ++k) {
#pragma unroll
        for (int t = 0; t < 4; ++t) {
            const bf16x8 bt =
                *(const bf16x8*)&W[(n0 + t * 16 + lcol) * 256 + k * 32 + grp * 8];
            acc[t] = __builtin_amdgcn_mfma_f32_16x16x32_bf16(af[k], bt, acc[t], 0, 0, 0);
        }
    }
#pragma unroll
    for (int t = 0; t < 4; ++t) {
        const int feat = n0 + t * 16 + lcol;
        const float bval = bias[feat];
        const int h = feat >> 5, d = feat & 31;
        if (wsel == 2) {
            uint2 o;
            o.x = (unsigned short)f2bf(acc[t][0] + bval) |
                  ((unsigned)(unsigned short)f2bf(acc[t][1] + bval) << 16);
            o.y = (unsigned short)f2bf(acc[t][2] + bval) |
                  ((unsigned)(unsigned short)f2bf(acc[t][3] + bval) << 16);
            *(uint2*)&vto[h * (HD * NTOK) + d * NTOK + m0 + grp * 4] = o;
        } else {
            short* __restrict__ out = (wsel == 0) ? qo : ko;
            // fold 1/sqrt(D) * log2(e) into Q so attn uses raw exp2
            const float sc = (wsel == 0) ? (QSCALE * LOG2E) : 1.0f;
#pragma unroll
            for (int j = 0; j < 4; ++j)
                out[h * (NTOK * HD) + (m0 + grp * 4 + j) * HD + d] =
                    f2bf((acc[t][j] + bval) * sc);
        }
    }
}

// ---- MFMA flash attention: counted-vmcnt pipeline, 3 buffers, raw barrier
__global__ __launch_bounds__(256) void attn_mfma(
    const short* __restrict__ qg, const short* __restrict__ kg,
    const short* __restrict__ vtg, const unsigned long long* __restrict__ maskT,
    float* __restrict__ o_part, float* __restrict__ l_part)
{
    const int h = blockIdx.y;
    const int split = blockIdx.z;
    const int q0 = blockIdx.x << 6;
    const short* __restrict__ Q  = qg  + h * (NTOK * HD);
    const short* __restrict__ K  = kg  + h * (NTOK * HD);
    const short* __restrict__ Vt = vtg + h * (HD * NTOK);

    __shared__ short Ks[3][64][32];      // 64B rows, DMA-linear
    __shared__ short Vs[3][32][64];      // 128B rows, octet-XOR swizzled
    __shared__ short P_lds[4][16][76];   // 152B rows (wave-private)

    const int tid = threadIdx.x;
    const int wv = tid >> 6;
    const int lane = tid & 63;
    const int grp = lane >> 4;
    const int lcol = lane & 15;
    const int q0w = q0 + wv * 16;
    const int wvu = __builtin_amdgcn_readfirstlane(wv);

    // DMA source lane-coords (dest is implicit: wave base + lane*16B)
    const int k_row = tid >> 2, k_oct = tid & 3;          // K: 64 rows x 4 oct
    const int v_row = tid >> 3;                           // V: 32 rows x 8 oct
    const int v_oct = (tid & 7) ^ (v_row & 7);            // pre-swizzled src
    const short* __restrict__ kbase = &K[k_row * HD + k_oct * 8];
    const short* __restrict__ vbase = &Vt[v_row * NTOK + v_oct * 8];

    // Q as B-operand: B[n=lcol(qrow)][k=grp*8+j(d)]
    const bf16x8 qfrag = *(const bf16x8*)&Q[(q0w + lcol) * HD + grp * 8];

    const int qb = __builtin_amdgcn_readfirstlane(blockIdx.x * 4 + wv);
    const unsigned long long* __restrict__ mbase = maskT + (size_t)qb * 1024;

    f32x4 ot[2] = {};     // O^T C-layout: row=grp*4+j (d), col=lcol (qrow)
    f32x4 lacc = {};      // column sums of P via mfma(ones, pf, .)
    const f32x4 cinit = {CINIT, CINIT, CINIT, CINIT};
    bf16x8 ones;
#pragma unroll
    for (int i = 0; i < 8; ++i) ones[i] = (short)0x3F80;   // bf16 1.0

    const int tps = 64 / (int)gridDim.z;   // 64-key tiles per split
    const int kt_begin = split * tps;
    const int kt_end = kt_begin + tps;

// async DMA one 64-key tile (4KB K + 4KB V) into buffer BUF; each wave
// fills its 1KB quarter (lane l -> wave_base + l*16B, HW-defined)
#define STAGE(BUF, KT)                                                       \
    {                                                                        \
        const int k0s = (KT) << 6;                                           \
        __builtin_amdgcn_global_load_lds(                                    \
            (gl_u8*)(kbase + k0s * HD),                                      \
            (lds_u8*)((unsigned char*)&Ks[BUF][0][0] + (wvu << 10)),         \
            16, 0, 0);                                                       \
        __builtin_amdgcn_global_load_lds(                                    \
            (gl_u8*)(vbase + k0s),                                           \
            (lds_u8*)((unsigned char*)&Vs[BUF][0][0] + (wvu << 10)),         \
            16, 0, 0);                                                       \
    }

    STAGE(0, kt_begin)
    if (kt_begin + 1 < kt_end) STAGE(1, kt_begin + 1)

    int cur = 0;
    for (int kt = kt_begin; kt < kt_end; ++kt) {
        // tile kt landed when <=2 VMEM ops (tile kt+1's stage) outstanding;
        // in-order retirement makes vmcnt(2) sufficient. Last iter: drain.
        if (kt + 1 < kt_end)
            asm volatile("s_waitcnt vmcnt(2)" ::: "memory");
        else
            asm volatile("s_waitcnt vmcnt(0)" ::: "memory");
        __builtin_amdgcn_s_barrier();
        __builtin_amdgcn_sched_barrier(0);

        // mask words first (scalar path; if vector, pre-use wait <= vmcnt(2))
        const u64x4* mp = (const u64x4*)(mbase + kt * 16);
        const u64x4 wa = mp[0], wb = mp[1], wc = mp[2], wd = mp[3];

        // stage tile kt+2 into the rotation buffer (= buffer of tile kt-1;
        // all waves passed the barrier, so kt-1 reads are complete)
        const int nxt = (cur == 0) ? 2 : cur - 1;
        if (kt + 2 < kt_end) STAGE(nxt, kt + 2)

        // fragments from shared LDS tiles
        bf16x8 kf[4], vf[4];
#pragma unroll
        for (int b = 0; b < 4; ++b)
            kf[b] = *(const bf16x8*)&Ks[cur][b * 16 + lcol][grp * 8];
#pragma unroll
        for (int c = 0; c < 2; ++c) {
            vf[c * 2 + 0] =
                *(const bf16x8*)&Vs[cur][c * 16 + lcol][(grp ^ (lcol & 7)) * 8];
            vf[c * 2 + 1] =
                *(const bf16x8*)&Vs[cur][c * 16 + lcol][((4 + grp) ^ (lcol & 7)) * 8];
        }

        // S^T = K Q^T - 8*log2e: row=key_in_blk, col=qrow (log2-domain)
        f32x4 s[4];
        __builtin_amdgcn_s_setprio(1);
#pragma unroll
        for (int b = 0; b < 4; ++b)
            s[b] = __builtin_amdgcn_mfma_f32_16x16x32_bf16(
                kf[b], qfrag, cinit, 0, 0, 0);
        __builtin_amdgcn_s_setprio(0);

        // p = exp2(s) masked; truncating v_perm pack; ds_write_b64
#pragma unroll
        for (int b = 0; b < 4; ++b) {
            const u64x4 wj = (b == 0) ? wa : (b == 1) ? wb : (b == 2) ? wc : wd;
            const float p0 = sel_mask(__builtin_amdgcn_exp2f(s[b][0]), wj[0]);
            const float p1 = sel_mask(__builtin_amdgcn_exp2f(s[b][1]), wj[1]);
            const float p2 = sel_mask(__builtin_amdgcn_exp2f(s[b][2]), wj[2]);
            const float p3 = sel_mask(__builtin_amdgcn_exp2f(s[b][3]), wj[3]);
            uint2 t;
            t.x = packtrunc(p0, p1);
            t.y = packtrunc(p2, p3);
            *(uint2*)&P_lds[wv][lcol][b * 16 + grp * 4] = t;
        }

        // P as B-operand: row-contiguous b64 pairs
        const uint2 pl0 = *(const uint2*)&P_lds[wv][lcol][grp * 8];
        const uint2 pl1 = *(const uint2*)&P_lds[wv][lcol][grp * 8 + 4];
        const uint2 pl2 = *(const uint2*)&P_lds[wv][lcol][32 + grp * 8];
        const uint2 pl3 = *(const uint2*)&P_lds[wv][lcol][32 + grp * 8 + 4];
        struct { uint2 a, b; } u0 = {pl0, pl1}, u1 = {pl2, pl3};
        const bf16x8 pf0 = __builtin_bit_cast(bf16x8, u0);
        const bf16x8 pf1 = __builtin_bit_cast(bf16x8, u1);

        __builtin_amdgcn_s_setprio(1);
#pragma unroll
        for (int c = 0; c < 2; ++c) {
            ot[c] = __builtin_amdgcn_mfma_f32_16x16x32_bf16(vf[c * 2 + 0], pf0, ot[c], 0, 0, 0);
            ot[c] = __builtin_amdgcn_mfma_f32_16x16x32_bf16(vf[c * 2 + 1], pf1, ot[c], 0, 0, 0);
        }
        lacc = __builtin_amdgcn_mfma_f32_16x16x32_bf16(ones, pf0, lacc, 0, 0, 0);
        lacc = __builtin_amdgcn_mfma_f32_16x16x32_bf16(ones, pf1, lacc, 0, 0, 0);
        __builtin_amdgcn_s_setprio(0);

        cur = (cur == 2) ? 0 : cur + 1;
    }
#undef STAGE

    float* __restrict__ ob = o_part + split * (NTOK * EDIM);
#pragma unroll
    for (int c = 0; c < 2; ++c) {
        float4 st;
        st.x = ot[c][0]; st.y = ot[c][1]; st.z = ot[c][2]; st.w = ot[c][3];
        *(float4*)&ob[(q0w + lcol) * EDIM + h * HD + c * 16 + grp * 4] = st;
    }
    // every lane holds l[qrow] in lacc[0] (A=ones -> all C-rows equal)
    if (grp == 0)
        l_part[split * (NTOK * HEADS) + (q0w + lcol) * HEADS + h] = lacc[0];
}

// ---- output projection, combine fused: Y = ((Σo)/(Σl)) @ Wo^T + bo -------
// R13 tiling: grid (64,4), 64 rows/block, 4 n-tiles per wave (af reused 4x).
// NS compile-time so split-loads fully unroll and overlap.
template <int NS>
__global__ __launch_bounds__(256) void out_mfma(
    const float* __restrict__ o_part, const float* __restrict__ l_part,
    const short* __restrict__ Wob, const float* __restrict__ bo,
    float* __restrict__ Y)
{
    const int tid = threadIdx.x;
    const int wv = tid >> 6, lane = tid & 63;
    const int grp = lane >> 4, lcol = lane & 15;
    const int n0 = blockIdx.y << 6;
    const int m0 = blockIdx.x * 64 + wv * 16;
    const int r = m0 + lcol;

    bf16x8 af[8];
#pragma unroll
    for (int k = 0; k < 8; ++k) {
        float4 s0 = {0.f, 0.f, 0.f, 0.f}, s1 = {0.f, 0.f, 0.f, 0.f};
        float lv = 0.f;
#pragma unroll
        for (int s = 0; s < NS; ++s) {
            const float* op = &o_part[s * (NTOK * EDIM) + r * EDIM + k * 32 + grp * 8];
            const float4 t0 = *(const float4*)op;
            const float4 t1 = *(const float4*)(op + 4);
            s0.x += t0.x; s0.y += t0.y; s0.z += t0.z; s0.w += t0.w;
            s1.x += t1.x; s1.y += t1.y; s1.z += t1.z; s1.w += t1.w;
            lv += l_part[s * (NTOK * HEADS) + r * HEADS + k];
        }
        const float inv = 1.0f / lv;
        bf16x8 t;
        t[0] = f2bf(s0.x * inv); t[1] = f2bf(s0.y * inv);
        t[2] = f2bf(s0.z * inv); t[3] = f2bf(s0.w * inv);
        t[4] = f2bf(s1.x * inv); t[5] = f2bf(s1.y * inv);
        t[6] = f2bf(s1.z * inv); t[7] = f2bf(s1.w * inv);
        af[k] = t;
    }

    f32x4 acc[4] = {};
#pragma unroll
    for (int k = 0; k < 8; ++k) {
#pragma unroll
        for (int t = 0; t < 4; ++t) {
            const bf16x8 bt =
                *(const bf16x8*)&Wob[(n0 + t * 16 + lcol) * 256 + k * 32 + grp * 8];
            acc[t] = __builtin_amdgcn_mfma_f32_16x16x32_bf16(af[k], bt, acc[t], 0, 0, 0);
        }
    }
#pragma unroll
    for (int t = 0; t < 4; ++t) {
        const float bval = bo[n0 + t * 16 + lcol];
#pragma unroll
        for (int j = 0; j < 4; ++j)
            Y[(m0 + grp * 4 + j) * EDIM + n0 + t * 16 + lcol] = acc[t][j] + bval;
    }
}

extern "C" void kernel_launch(void* const* d_in, const int* in_sizes, int n_in,
                              void* d_out, int out_size, void* d_ws, size_t ws_size,
                              hipStream_t stream) {
    (void)in_sizes; (void)n_in; (void)out_size; (void)ws_size;
    const float* x  = (const float*)d_in[0];
    const int*  adj = (const int*)d_in[1];
    const float* Wq = (const float*)d_in[2];
    const float* bq = (const float*)d_in[3];
    const float* Wk = (const float*)d_in[4];
    const float* bk = (const float*)d_in[5];
    const float* Wv = (const float*)d_in[6];
    const float* bv = (const float*)d_in[7];
    const float* Wo = (const float*)d_in[8];
    const float* bo = (const float*)d_in[9];

    char* ws = (char*)d_ws;
    short* x_bf  = (short*)(ws);                        // 2 MB  [N][256]
    short* q_ws  = (short*)(ws + (2u << 20));           // 2 MB  [H][N][32]
    short* k_ws  = (short*)(ws + (4u << 20));           // 2 MB
    short* vt_ws = (short*)(ws + (6u << 20));           // 2 MB  [H][32][N]
    unsigned long long* maskT =
        (unsigned long long*)(ws + (8u << 20));         // 2 MB
    short* Wq_bf = (short*)(ws + (10u << 20));          // 128 KB each
    short* Wk_bf = Wq_bf + (EDIM * EDIM);
    short* Wv_bf = Wk_bf + (EDIM * EDIM);
    short* Wo_bf = Wv_bf + (EDIM * EDIM);
    float* l_part = (float*)(ws + (11u << 20));         // 256 KB [2][N][8]
    float* o_part = (float*)(ws + (12u << 20));         // 8 MB   [2][N][256]

    prep<<<dim3(2048 + 1280), 256, 0, stream>>>(
        adj, maskT, x, Wq, Wk, Wv, Wo, x_bf, Wq_bf, Wk_bf, Wv_bf, Wo_bf);
    qkv_mfma<<<dim3(64, 12), 256, 0, stream>>>(x_bf, Wq_bf, Wk_bf, Wv_bf,
                                               bq, bk, bv, q_ws, k_ws, vt_ws);
    attn_mfma<<<dim3(64, HEADS, NSPLIT), 256, 0, stream>>>(
        q_ws, k_ws, vt_ws, maskT, o_part, l_part);
    out_mfma<NSPLIT><<<dim3(64, 4), 256, 0, stream>>>(o_part, l_part, Wo_bf, bo,
                                                      (float*)d_out);
}